// Round 19
// baseline (215.152 us; speedup 1.0000x reference)
//
#include <hip/hip_runtime.h>
#include <hip/hip_bf16.h>
#include <stdint.h>

#define B_ 2
#define S_ 1024
#define H_ 16
#define D_ 128
#define HID 2048
#define POS_ 1024
#define L_ 2048
#define NQKV 6144

using f32x4  = __attribute__((ext_vector_type(4))) float;
using bf16x8 = __attribute__((ext_vector_type(8))) short;
using us4    = __attribute__((ext_vector_type(4))) unsigned short;
using us8    = __attribute__((ext_vector_type(8))) unsigned short;

typedef const __attribute__((address_space(1))) void* gp_t;
typedef __attribute__((address_space(3))) void* lp_t;

__device__ __forceinline__ unsigned short f2bf(float f){
  union { __hip_bfloat16 h; unsigned short u; } cv;
  cv.h = __float2bfloat16(f);
  return cv.u;
}
__device__ __forceinline__ float bf2f(unsigned short u){
  return __uint_as_float(((uint32_t)u) << 16);
}

// MEGA-PREP: weights cvt (blocks 0..16383), x cvt (..20479), k-cache cvt
// (..24575), mask->fragment-bf16 (..25599), bias gather (..25605).
__global__ void k_prep(const float* __restrict__ wq, const float* __restrict__ wk,
    const float* __restrict__ wv, const float* __restrict__ wo,
    const float* __restrict__ x, const float* __restrict__ mask,
    const float* __restrict__ kc, const float* __restrict__ bq,
    const float* __restrict__ bk, const float* __restrict__ bv,
    unsigned short* __restrict__ Wqkvb, unsigned short* __restrict__ Wob,
    unsigned short* __restrict__ xb, unsigned short* __restrict__ mf,
    unsigned short* __restrict__ kf, float* __restrict__ bqkv)
{
  int blk = blockIdx.x, tid = threadIdx.x;
  if (blk < 16384){
    int which = blk >> 12;
    int i = ((blk & 4095)*256 + tid)*4;
    const float* src = which==0?wq:which==1?wk:which==2?wv:wo;
    unsigned short* dst = which==0?Wqkvb:which==1?Wqkvb+4194304:which==2?Wqkvb+8388608:Wob;
    float4 v = *(const float4*)(src + i);
    us4 o; o[0]=f2bf(v.x); o[1]=f2bf(v.y); o[2]=f2bf(v.z); o[3]=f2bf(v.w);
    *(us4*)(dst + i) = o;
  } else if (blk < 20480){
    int i = ((blk - 16384)*256 + tid)*4;
    float4 v = *(const float4*)(x + i);
    us4 o; o[0]=f2bf(v.x); o[1]=f2bf(v.y); o[2]=f2bf(v.z); o[3]=f2bf(v.w);
    *(us4*)(xb + i) = o;
  } else if (blk < 24576){
    int i = ((blk - 20480)*256 + tid)*4;
    int b = i >> 21;
    int rem = i & ((1 << 21) - 1);
    size_t src = (size_t)b * (2*POS_*H_*D_) + rem;
    size_t dst = (size_t)b * (L_*H_*D_) + rem;
    float4 k4 = *(const float4*)(kc + src);
    us4 ko; ko[0]=f2bf(k4.x); ko[1]=f2bf(k4.y); ko[2]=f2bf(k4.z); ko[3]=f2bf(k4.w);
    *(us4*)(kf + dst) = ko;
  } else if (blk < 25600){
    int idx = (blk - 24576)*256 + tid;      // < 262144
    int lr = idx & 15, lg = (idx >> 4) & 3, tt = (idx >> 6) & 31;
    int qg = (idx >> 11) & 63, par = idx >> 17;
    const float LOG2E = 1.4426950408889634f;
    const float* src = mask + (size_t)par*4194304 + 2097152;
    unsigned short o[16];
    #pragma unroll
    for (int nf=0; nf<4; ++nf)
      #pragma unroll
      for (int i2=0; i2<4; ++i2){
        int q = qg*16 + lg*4 + i2;
        int t = tt*64 + nf*16 + lr;
        o[nf*4+i2] = f2bf(src[(size_t)q*2048 + t] * LOG2E);
      }
    us8* dst = (us8*)(mf + (size_t)idx*16);
    dst[0] = *(const us8*)&o[0];
    dst[1] = *(const us8*)&o[8];
  } else {
    int i = ((blk - 25600)*256 + tid)*4;    // 0..6143
    float4 v = (i < 2048) ? *(const float4*)(bq + i)
             : (i < 4096) ? *(const float4*)(bk + i - 2048)
                          : *(const float4*)(bv + i - 4096);
    *(float4*)(bqkv + i) = v;
  }
}

// Merged rope (blocks 0..8191) + V^T build (blocks 8192..9215).
__global__ __launch_bounds__(256) void k_rv(const unsigned short* __restrict__ qkvb,
    const float* __restrict__ cosb, const float* __restrict__ sinb,
    const float* __restrict__ vc,
    float* __restrict__ kout, unsigned short* __restrict__ qb,
    unsigned short* __restrict__ kf, unsigned short* __restrict__ vt,
    float* __restrict__ vout)
{
  __shared__ unsigned short T[64*130];
  int blk = blockIdx.x, tid = threadIdx.x;
  if (blk < 8192){
    int idx = blk*256 + tid;
    int j  = idx & 63;
    int hh = (idx >> 6) & 15;
    int s  = (idx >> 10) & 1023;
    int b  = idx >> 20;
    int m  = b*S_ + s;
    float c  = cosb[(POS_ + s)*64 + j];
    float sn = sinb[(POS_ + s)*64 + j];
    size_t base = (size_t)m*NQKV + hh*D_ + j;
    float q1 = bf2f(qkvb[base]),          q2 = bf2f(qkvb[base + 64]);
    float k1 = bf2f(qkvb[base + HID]),    k2 = bf2f(qkvb[base + HID + 64]);
    float qr = c*q1 - sn*q2, qi = sn*q1 + c*q2;
    float kr = c*k1 - sn*k2, ki = sn*k1 + c*k2;
    const float SCQ = 0.12751743232994544f;   // (1/sqrt(128)) * log2e
    size_t o = (size_t)m*HID + hh*D_ + j;
    kout[o] = kr; kout[o + 64] = ki;
    qb[o] = f2bf(qr*SCQ); qb[o + 64] = f2bf(qi*SCQ);
    size_t fo = ((size_t)(b*L_ + POS_ + s)*H_ + hh)*D_ + j;
    kf[fo] = f2bf(kr); kf[fo + 64] = f2bf(ki);
    return;
  }
  int vb = blk - 8192;
  int tt = vb & 31, h = (vb >> 5) & 15, b = vb >> 9;
  int t0 = tt * 64;
  int d0 = (tid & 31) * 4, tr = tid >> 5;
  #pragma unroll
  for (int pass=0; pass<8; ++pass){
    int t = tr + pass*8;
    int gt = t0 + t;
    us4 o;
    if (gt < POS_){
      float4 v4 = *(const float4*)(vc + (((size_t)(b*2*POS_ + gt))*H_ + h)*D_ + d0);
      o[0]=f2bf(v4.x); o[1]=f2bf(v4.y); o[2]=f2bf(v4.z); o[3]=f2bf(v4.w);
    } else {
      o = *(const us4*)(qkvb + (size_t)(b*S_ + gt - POS_)*NQKV + 2*HID + h*D_ + d0);
      float4 vf4;
      vf4.x = bf2f(o[0]); vf4.y = bf2f(o[1]); vf4.z = bf2f(o[2]); vf4.w = bf2f(o[3]);
      *(float4*)(vout + (size_t)(b*S_ + gt - POS_)*HID + h*D_ + d0) = vf4;
    }
    *(us4*)(&T[t*130 + d0]) = o;
  }
  __syncthreads();
  int d = tid >> 1, th = (tid & 1) * 32;
  uint4 buf4[4];
  unsigned short* buf = (unsigned short*)buf4;
  #pragma unroll
  for (int e=0;e<32;++e) buf[e] = T[(th+e)*130 + d];
  unsigned short* dst = vt + (((size_t)(b*H_ + h)*D_ + d)*L_) + t0 + th;
  #pragma unroll
  for (int c=0;c<4;++c) *(uint4*)(dst + c*8) = buf4[c];
}

// QKV GEMM, XCD-swizzled (each XCD owns 6 B-columns: 3.1 MB < 4 MB L2).
__global__ __launch_bounds__(256) void k_gemm(const unsigned short* __restrict__ A,
    const unsigned short* __restrict__ Bm, const float* __restrict__ bias,
    unsigned short* __restrict__ Cout, int Md, int Nd, int Kd)
{
  __shared__ unsigned short As[128*64];
  __shared__ unsigned short Bs[128*64];
  const int tid = threadIdx.x;
  const int lane = tid & 63, w = tid >> 6;
  const int wr = w >> 1, wc = w & 1;
  const int lg = lane >> 4, lr = lane & 15;
  const int xcd = blockIdx.x & 7, kk = blockIdx.x >> 3;
  const int tn = xcd*6 + (kk % 6);
  const int tm = kk / 6;
  f32x4 acc[4][4];
  #pragma unroll
  for (int i=0;i<4;++i)
    #pragma unroll
    for (int j=0;j<4;++j){ f32x4 z = {0.f,0.f,0.f,0.f}; acc[i][j] = z; }

  for (int k0 = 0; k0 < Kd; k0 += 64){
    #pragma unroll
    for (int j=0;j<4;++j){
      int chunk = j*256 + w*64 + lane;
      int row = chunk >> 3, cc = chunk & 7;
      int ccs = cc ^ (row & 7);
      const unsigned short* ga = A  + (size_t)(tm*128 + row)*Kd + k0 + ccs*8;
      __builtin_amdgcn_global_load_lds((gp_t)ga,
          (lp_t)((char*)As + (j*256 + w*64)*16), 16, 0, 0);
      const unsigned short* gb = Bm + (size_t)(tn*128 + row)*Kd + k0 + ccs*8;
      __builtin_amdgcn_global_load_lds((gp_t)gb,
          (lp_t)((char*)Bs + (j*256 + w*64)*16), 16, 0, 0);
    }
    __syncthreads();
    #pragma unroll
    for (int ks=0; ks<2; ++ks){
      bf16x8 af[4], bf[4];
      #pragma unroll
      for (int mi=0;mi<4;++mi){
        int row = wr*64 + mi*16 + lr;
        int byte = (row*128 + ks*64 + lg*16) ^ ((row & 7) << 4);
        af[mi] = *(const bf16x8*)((const char*)As + byte);
      }
      #pragma unroll
      for (int ni=0;ni<4;++ni){
        int row = wc*64 + ni*16 + lr;
        int byte = (row*128 + ks*64 + lg*16) ^ ((row & 7) << 4);
        bf[ni] = *(const bf16x8*)((const char*)Bs + byte);
      }
      #pragma unroll
      for (int mi=0;mi<4;++mi)
        #pragma unroll
        for (int ni=0;ni<4;++ni)
          acc[mi][ni] = __builtin_amdgcn_mfma_f32_16x16x32_bf16(af[mi], bf[ni], acc[mi][ni], 0, 0, 0);
    }
    __syncthreads();
  }
  #pragma unroll
  for (int mi=0;mi<4;++mi)
    #pragma unroll
    for (int ni=0;ni<4;++ni){
      int col = tn*128 + wc*64 + ni*16 + lr;
      float bv = bias[col];
      #pragma unroll
      for (int i=0;i<4;++i){
        int row = tm*128 + wr*64 + mi*16 + lg*4 + i;
        Cout[(size_t)row*Nd + col] = f2bf(acc[mi][ni][i] + bv);
      }
    }
}

// Split-K=4 out-proj GEMM, XCD-swizzled; bf16 quarter-partials.
__global__ __launch_bounds__(256) void k_gemm_sk(const unsigned short* __restrict__ A,
    const unsigned short* __restrict__ Bm, unsigned short* __restrict__ Cp, int Md, int Nd, int Kd)
{
  __shared__ unsigned short As[128*64];
  __shared__ unsigned short Bs[128*64];
  const int tid = threadIdx.x;
  const int lane = tid & 63, w = tid >> 6;
  const int wr = w >> 1, wc = w & 1;
  const int lg = lane >> 4, lr = lane & 15;
  const int quarter = blockIdx.x >> 8;
  const int lbid = blockIdx.x & 255;
  const int xcd = lbid & 7, kk = lbid >> 3;
  const int tn = xcd*2 + (kk & 1);
  const int tm = kk >> 1;
  const int koff = quarter * (Kd >> 2);
  f32x4 acc[4][4];
  #pragma unroll
  for (int i=0;i<4;++i)
    #pragma unroll
    for (int j=0;j<4;++j){ f32x4 z = {0.f,0.f,0.f,0.f}; acc[i][j] = z; }

  for (int k0 = koff; k0 < koff + (Kd >> 2); k0 += 64){
    #pragma unroll
    for (int j=0;j<4;++j){
      int chunk = j*256 + w*64 + lane;
      int row = chunk >> 3, cc = chunk & 7;
      int ccs = cc ^ (row & 7);
      const unsigned short* ga = A  + (size_t)(tm*128 + row)*Kd + k0 + ccs*8;
      __builtin_amdgcn_global_load_lds((gp_t)ga,
          (lp_t)((char*)As + (j*256 + w*64)*16), 16, 0, 0);
      const unsigned short* gb = Bm + (size_t)(tn*128 + row)*Kd + k0 + ccs*8;
      __builtin_amdgcn_global_load_lds((gp_t)gb,
          (lp_t)((char*)Bs + (j*256 + w*64)*16), 16, 0, 0);
    }
    __syncthreads();
    #pragma unroll
    for (int ks=0; ks<2; ++ks){
      bf16x8 af[4], bf[4];
      #pragma unroll
      for (int mi=0;mi<4;++mi){
        int row = wr*64 + mi*16 + lr;
        int byte = (row*128 + ks*64 + lg*16) ^ ((row & 7) << 4);
        af[mi] = *(const bf16x8*)((const char*)As + byte);
      }
      #pragma unroll
      for (int ni=0;ni<4;++ni){
        int row = wc*64 + ni*16 + lr;
        int byte = (row*128 + ks*64 + lg*16) ^ ((row & 7) << 4);
        bf[ni] = *(const bf16x8*)((const char*)Bs + byte);
      }
      #pragma unroll
      for (int mi=0;mi<4;++mi)
        #pragma unroll
        for (int ni=0;ni<4;++ni)
          acc[mi][ni] = __builtin_amdgcn_mfma_f32_16x16x32_bf16(af[mi], bf[ni], acc[mi][ni], 0, 0, 0);
    }
    __syncthreads();
  }
  unsigned short* Cb = Cp + (size_t)quarter*Md*Nd;
  #pragma unroll
  for (int mi=0;mi<4;++mi)
    #pragma unroll
    for (int ni=0;ni<4;++ni){
      int col = tn*128 + wc*64 + ni*16 + lr;
      #pragma unroll
      for (int i=0;i<4;++i){
        int row = tm*128 + wr*64 + mi*16 + lg*4 + i;
        Cb[(size_t)row*Nd + col] = f2bf(acc[mi][ni][i]);
      }
    }
}

// out = sum(Cp[0..3]) + bias  (bf16 partials -> fp32 out)
__global__ void k_red(const unsigned short* __restrict__ Cp, const float* __restrict__ bias,
                      float* __restrict__ out){
  int i = (blockIdx.x*256 + threadIdx.x)*4;
  if (i >= 2048*2048) return;
  int col = i & 2047;
  float4 bv = *(const float4*)(bias + col);
  float4 r; r.x = bv.x; r.y = bv.y; r.z = bv.z; r.w = bv.w;
  #pragma unroll
  for (int q=0; q<4; ++q){
    us4 a = *(const us4*)(Cp + (size_t)q*4194304 + i);
    r.x += bf2f(a[0]); r.y += bf2f(a[1]); r.z += bf2f(a[2]); r.w += bf2f(a[3]);
  }
  *(float4*)(out + i) = r;
}

// Flash attention: QBLK=256 (8 waves x 32 q-rows share one K/V tile -> staging
// per q-row halves).  split=2, no max-tracking, l via MFMA ones-column, T5.
__global__ __launch_bounds__(512, 1) void k_attn_part(const unsigned short* __restrict__ Q,
    const unsigned short* __restrict__ Kf, const unsigned short* __restrict__ vt,
    const unsigned short* __restrict__ mf, unsigned short* __restrict__ Opart,
    float* __restrict__ ml)
{
  __shared__ unsigned short Kt[64*128];     // 16 KB
  __shared__ unsigned short Vt[144*64];     // 18 KB
  __shared__ unsigned short Pw[8][32*64];   // 32 KB
  const int tid = threadIdx.x;
  const int lane = tid & 63, w = tid >> 6;  // w 0..7
  const int lg = lane >> 4, lr = lane & 15;
  // 256 blocks: xcd = bid&7; each XCD owns 8 (split,b,h) panels (4 qblks each).
  const int hw = blockIdx.x;
  const int xcd = hw & 7, slot = hw >> 3;   // slot 0..31
  const int g = xcd*8 + (slot >> 2);        // 0..63
  const int qblk = slot & 3;                // 0..3 (256 q each)
  const int h = g & 15, b = (g >> 4) & 1, split = g >> 5;
  const int q0 = qblk * 256;
  const int tlo = split * (L_/2);

  {
    uint32_t* vz = (uint32_t*)&Vt[128*64];  // rows 128..143 = 512 u32
    vz[tid] = (tid < 32) ? 0x3F803F80u : 0u;
  }

  bf16x8 qf[2][4];
  #pragma unroll
  for (int qh=0; qh<2; ++qh){
    const unsigned short* qbase = Q + ((size_t)(b*S_ + q0 + w*32 + qh*16 + lr))*HID + h*D_;
    #pragma unroll
    for (int ks=0; ks<4; ++ks)
      qf[qh][ks] = *(const bf16x8*)(qbase + ks*32 + lg*8);
  }
  f32x4 oacc[2][9];
  #pragma unroll
  for (int qh=0; qh<2; ++qh)
    #pragma unroll
    for (int i=0;i<9;++i){ f32x4 z = {0.f,0.f,0.f,0.f}; oacc[qh][i] = z; }
  const unsigned short* vtb = vt + ((size_t)(b*H_ + h)*D_)*L_;
  const unsigned short* mfrag[2];
  #pragma unroll
  for (int qh=0; qh<2; ++qh)
    mfrag[qh] = mf + ((size_t)((h & 1)*64 + qblk*16 + w*2 + qh) * 32) * 1024
                   + (size_t)(lg*16 + lr) * 16;

  for (int tof = 0; tof < L_/2; tof += 64){
    int t0 = tlo + tof;
    // stage K [64][128]: 1024 chunks, 512 threads x 2
    #pragma unroll
    for (int j=0;j<2;++j){
      int chunk = j*512 + tid;
      int row = chunk >> 4, cc = chunk & 15;
      int ccs = cc ^ (row & 7);
      const unsigned short* gk = Kf + ((size_t)(b*L_ + t0 + row)*H_ + h)*D_ + ccs*8;
      __builtin_amdgcn_global_load_lds((gp_t)gk,
          (lp_t)((char*)Kt + chunk*16), 16, 0, 0);
    }
    // stage V^T [128][64]
    #pragma unroll
    for (int j=0;j<2;++j){
      int chunk = j*512 + tid;
      int row = chunk >> 3, cc = chunk & 7;
      int ccs = cc ^ (row & 7);
      const unsigned short* gv = vtb + (size_t)row*L_ + t0 + ccs*8;
      __builtin_amdgcn_global_load_lds((gp_t)gv,
          (lp_t)((char*)Vt + chunk*16), 16, 0, 0);
    }
    union { us8 v[2]; unsigned short s[16]; } mu[2];
    #pragma unroll
    for (int qh=0; qh<2; ++qh){
      const us8* mv = (const us8*)(mfrag[qh] + (size_t)(tof >> 6)*1024 + (size_t)(split ? 16384 : 0));
      mu[qh].v[0] = mv[0]; mu[qh].v[1] = mv[1];
    }
    __syncthreads();

    f32x4 sc[2][4];
    #pragma unroll
    for (int qh=0; qh<2; ++qh)
      #pragma unroll
      for (int nf=0;nf<4;++nf){ f32x4 z = {0.f,0.f,0.f,0.f}; sc[qh][nf] = z; }
    __builtin_amdgcn_s_setprio(1);
    #pragma unroll
    for (int nf=0;nf<4;++nf){
      #pragma unroll
      for (int ks=0;ks<4;++ks){
        int row = nf*16 + lr;
        int byte = (row*256 + ks*64 + lg*16) ^ ((row & 7) << 4);
        bf16x8 kb = *(const bf16x8*)((const char*)Kt + byte);
        sc[0][nf] = __builtin_amdgcn_mfma_f32_16x16x32_bf16(qf[0][ks], kb, sc[0][nf], 0, 0, 0);
        sc[1][nf] = __builtin_amdgcn_mfma_f32_16x16x32_bf16(qf[1][ks], kb, sc[1][nf], 0, 0, 0);
      }
    }
    __builtin_amdgcn_s_setprio(0);

    #pragma unroll
    for (int qh=0; qh<2; ++qh)
      #pragma unroll
      for (int nf=0;nf<4;++nf)
        #pragma unroll
        for (int i=0;i<4;++i){
          float p = __builtin_amdgcn_exp2f(sc[qh][nf][i] + bf2f(mu[qh].s[nf*4+i]));
          int row = qh*16 + lg*4 + i;
          int byte = (row*128 + nf*32 + lr*2) ^ ((row & 7) << 4);
          *(unsigned short*)((char*)(&Pw[w][0]) + byte) = f2bf(p);
        }
    __asm__ volatile("s_waitcnt lgkmcnt(0)" ::: "memory");

    bf16x8 pa[2][2];
    #pragma unroll
    for (int qh=0; qh<2; ++qh)
      #pragma unroll
      for (int ks2=0; ks2<2; ++ks2){
        int row = qh*16 + lr;
        int pbyte = (row*128 + ks2*64 + lg*16) ^ ((row & 7) << 4);
        pa[qh][ks2] = *(const bf16x8*)((const char*)(&Pw[w][0]) + pbyte);
      }
    __builtin_amdgcn_s_setprio(1);
    #pragma unroll
    for (int ks2=0; ks2<2; ++ks2){
      #pragma unroll
      for (int df=0;df<9;++df){
        int vrow = df*16 + lr;
        int vbyte = (vrow*128 + ks2*64 + lg*16) ^ ((vrow & 7) << 4);
        bf16x8 vb = *(const bf16x8*)((const char*)Vt + vbyte);
        oacc[0][df] = __builtin_amdgcn_mfma_f32_16x16x32_bf16(pa[0][ks2], vb, oacc[0][df], 0, 0, 0);
        oacc[1][df] = __builtin_amdgcn_mfma_f32_16x16x32_bf16(pa[1][ks2], vb, oacc[1][df], 0, 0, 0);
      }
    }
    __builtin_amdgcn_s_setprio(0);
    __syncthreads();
  }

  #pragma unroll
  for (int qh=0; qh<2; ++qh){
    size_t rbase = (size_t)(b*H_ + h)*S_ + q0 + w*32 + qh*16;
    size_t pbase = (size_t)split*(B_*H_*S_) + rbase;
    #pragma unroll
    for (int df=0;df<8;++df)
      #pragma unroll
      for (int i=0;i<4;++i)
        Opart[(pbase + lg*4 + i)*D_ + df*16 + lr] = f2bf(oacc[qh][df][i]);
    if (lr == 0){
      #pragma unroll
      for (int i=0;i<4;++i){
        size_t row = pbase + lg*4 + i;
        ml[row*2]     = 0.0f;
        ml[row*2 + 1] = oacc[qh][8][i];
      }
    }
  }
}

// Combine 2 splits (weights exactly 1 since m==0).  bf16 Opart.
__global__ void k_comb(const unsigned short* __restrict__ Opart, const float* __restrict__ ml,
                       unsigned short* __restrict__ Ob)
{
  const int NR = B_*H_*S_;
  int idx = blockIdx.x*256 + threadIdx.x;
  int r = idx >> 5, dq = (idx & 31) * 4;
  float l0 = ml[(size_t)r*2 + 1];
  float l1 = ml[(size_t)(NR + r)*2 + 1];
  float inv = 1.0f / (l0 + l1);
  us4 o0 = *(const us4*)(Opart + (size_t)r*D_ + dq);
  us4 o1 = *(const us4*)(Opart + (size_t)(NR + r)*D_ + dq);
  int s = r & (S_-1), bh = r >> 10;
  int b = bh >> 4, h = bh & 15;
  size_t o = ((size_t)(b*S_ + s))*HID + h*D_ + dq;
  us4 w;
  w[0] = f2bf((bf2f(o0[0]) + bf2f(o1[0]))*inv);
  w[1] = f2bf((bf2f(o0[1]) + bf2f(o1[1]))*inv);
  w[2] = f2bf((bf2f(o0[2]) + bf2f(o1[2]))*inv);
  w[3] = f2bf((bf2f(o0[3]) + bf2f(o1[3]))*inv);
  *(us4*)(Ob + o) = w;
}

extern "C" void kernel_launch(void* const* d_in, const int* in_sizes, int n_in,
                              void* d_out, int out_size, void* d_ws, size_t ws_size,
                              hipStream_t stream){
  const float* x    = (const float*)d_in[0];
  const float* mask = (const float*)d_in[1];
  const float* cosb = (const float*)d_in[2];
  const float* sinb = (const float*)d_in[3];
  const float* kc   = (const float*)d_in[4];
  const float* vc   = (const float*)d_in[5];
  const float* Wq   = (const float*)d_in[8];
  const float* bq   = (const float*)d_in[9];
  const float* Wk   = (const float*)d_in[10];
  const float* bk   = (const float*)d_in[11];
  const float* Wv   = (const float*)d_in[12];
  const float* bv   = (const float*)d_in[13];
  const float* Wo   = (const float*)d_in[14];
  const float* bo   = (const float*)d_in[15];

  float* out  = (float*)d_out;
  float* kout = out + 4194304;
  float* vout = out + 8388608;

  char* ws = (char*)d_ws;
  unsigned short* qkvb  = (unsigned short*)(ws);             // 25165824 B (dead after k_rv)
  unsigned short* Opart = (unsigned short*)(ws);             // 16777216 B bf16, overlays dead qkvb
  unsigned short* Cp    = (unsigned short*)(ws);             // 33554432 B bf16 (4 quarters), after k_comb
  float*          ml    = (float*)(ws + 33554432);           // 524288 B
  unsigned short* xb    = (unsigned short*)(ws + 50331648);  // 8388608
  unsigned short* Wqkvb = (unsigned short*)(ws + 58720256);  // 25165824
  unsigned short* mf    = (unsigned short*)(ws + 83886080);  // 8388608
  unsigned short* Wob   = (unsigned short*)(ws + 92274688);  // 8388608
  float*          bqkv  = (float*)(ws + 100663296);          // 24576
  unsigned short* qb    = (unsigned short*)(ws + 100687872); // 8388608
  unsigned short* kf    = (unsigned short*)(ws + 109076480); // 16777216
  unsigned short* vt    = (unsigned short*)(ws + 125853696); // 16777216
  unsigned short* attnb = (unsigned short*)(ws + 142630912); // 8388608

  k_prep<<<25606, 256, 0, stream>>>(Wq, Wk, Wv, Wo, x, mask, kc, bq, bk, bv,
                                    Wqkvb, Wob, xb, mf, kf, bqkv);
  k_gemm<<<768, 256, 0, stream>>>(xb, Wqkvb, bqkv, qkvb, 2048, 6144, 2048);
  k_rv<<<9216, 256, 0, stream>>>(qkvb, cosb, sinb, vc, kout, qb, kf, vt, vout);
  k_attn_part<<<256, 512, 0, stream>>>(qb, kf, vt, mf, Opart, ml);
  k_comb<<<4096, 256, 0, stream>>>(Opart, ml, attnb);
  k_gemm_sk<<<1024, 256, 0, stream>>>(attnb, Wob, Cp, 2048, 2048, 2048);
  k_red<<<4096, 256, 0, stream>>>(Cp, bo, out);

  (void)in_sizes; (void)n_in; (void)out_size; (void)ws_size;
}

// Round 20
// 207.489 us; speedup vs baseline: 1.0369x; 1.0369x over previous
//
#include <hip/hip_runtime.h>
#include <hip/hip_bf16.h>
#include <stdint.h>

#define B_ 2
#define S_ 1024
#define H_ 16
#define D_ 128
#define HID 2048
#define POS_ 1024
#define L_ 2048
#define NQKV 6144

using f32x4  = __attribute__((ext_vector_type(4))) float;
using bf16x8 = __attribute__((ext_vector_type(8))) short;
using us4    = __attribute__((ext_vector_type(4))) unsigned short;
using us8    = __attribute__((ext_vector_type(8))) unsigned short;

typedef const __attribute__((address_space(1))) void* gp_t;
typedef __attribute__((address_space(3))) void* lp_t;

__device__ __forceinline__ unsigned short f2bf(float f){
  union { __hip_bfloat16 h; unsigned short u; } cv;
  cv.h = __float2bfloat16(f);
  return cv.u;
}
__device__ __forceinline__ float bf2f(unsigned short u){
  return __uint_as_float(((uint32_t)u) << 16);
}

// MEGA-PREP: weights cvt (blocks 0..16383), x cvt (..20479), k-cache cvt
// (..24575), mask->fragment-bf16 (..25599), bias gather (..25605).
__global__ void k_prep(const float* __restrict__ wq, const float* __restrict__ wk,
    const float* __restrict__ wv, const float* __restrict__ wo,
    const float* __restrict__ x, const float* __restrict__ mask,
    const float* __restrict__ kc, const float* __restrict__ bq,
    const float* __restrict__ bk, const float* __restrict__ bv,
    unsigned short* __restrict__ Wqkvb, unsigned short* __restrict__ Wob,
    unsigned short* __restrict__ xb, unsigned short* __restrict__ mf,
    unsigned short* __restrict__ kf, float* __restrict__ bqkv)
{
  int blk = blockIdx.x, tid = threadIdx.x;
  if (blk < 16384){
    int which = blk >> 12;
    int i = ((blk & 4095)*256 + tid)*4;
    const float* src = which==0?wq:which==1?wk:which==2?wv:wo;
    unsigned short* dst = which==0?Wqkvb:which==1?Wqkvb+4194304:which==2?Wqkvb+8388608:Wob;
    float4 v = *(const float4*)(src + i);
    us4 o; o[0]=f2bf(v.x); o[1]=f2bf(v.y); o[2]=f2bf(v.z); o[3]=f2bf(v.w);
    *(us4*)(dst + i) = o;
  } else if (blk < 20480){
    int i = ((blk - 16384)*256 + tid)*4;
    float4 v = *(const float4*)(x + i);
    us4 o; o[0]=f2bf(v.x); o[1]=f2bf(v.y); o[2]=f2bf(v.z); o[3]=f2bf(v.w);
    *(us4*)(xb + i) = o;
  } else if (blk < 24576){
    int i = ((blk - 20480)*256 + tid)*4;
    int b = i >> 21;
    int rem = i & ((1 << 21) - 1);
    size_t src = (size_t)b * (2*POS_*H_*D_) + rem;
    size_t dst = (size_t)b * (L_*H_*D_) + rem;
    float4 k4 = *(const float4*)(kc + src);
    us4 ko; ko[0]=f2bf(k4.x); ko[1]=f2bf(k4.y); ko[2]=f2bf(k4.z); ko[3]=f2bf(k4.w);
    *(us4*)(kf + dst) = ko;
  } else if (blk < 25600){
    int idx = (blk - 24576)*256 + tid;      // < 262144
    int lr = idx & 15, lg = (idx >> 4) & 3, tt = (idx >> 6) & 31;
    int qg = (idx >> 11) & 63, par = idx >> 17;
    const float LOG2E = 1.4426950408889634f;
    const float* src = mask + (size_t)par*4194304 + 2097152;
    unsigned short o[16];
    #pragma unroll
    for (int nf=0; nf<4; ++nf)
      #pragma unroll
      for (int i2=0; i2<4; ++i2){
        int q = qg*16 + lg*4 + i2;
        int t = tt*64 + nf*16 + lr;
        o[nf*4+i2] = f2bf(src[(size_t)q*2048 + t] * LOG2E);
      }
    us8* dst = (us8*)(mf + (size_t)idx*16);
    dst[0] = *(const us8*)&o[0];
    dst[1] = *(const us8*)&o[8];
  } else {
    int i = ((blk - 25600)*256 + tid)*4;    // 0..6143
    float4 v = (i < 2048) ? *(const float4*)(bq + i)
             : (i < 4096) ? *(const float4*)(bk + i - 2048)
                          : *(const float4*)(bv + i - 4096);
    *(float4*)(bqkv + i) = v;
  }
}

// Merged rope (blocks 0..8191) + V^T build (blocks 8192..9215).
__global__ __launch_bounds__(256) void k_rv(const unsigned short* __restrict__ qkvb,
    const float* __restrict__ cosb, const float* __restrict__ sinb,
    const float* __restrict__ vc,
    float* __restrict__ kout, unsigned short* __restrict__ qb,
    unsigned short* __restrict__ kf, unsigned short* __restrict__ vt,
    float* __restrict__ vout)
{
  __shared__ unsigned short T[64*130];
  int blk = blockIdx.x, tid = threadIdx.x;
  if (blk < 8192){
    int idx = blk*256 + tid;
    int j  = idx & 63;
    int hh = (idx >> 6) & 15;
    int s  = (idx >> 10) & 1023;
    int b  = idx >> 20;
    int m  = b*S_ + s;
    float c  = cosb[(POS_ + s)*64 + j];
    float sn = sinb[(POS_ + s)*64 + j];
    size_t base = (size_t)m*NQKV + hh*D_ + j;
    float q1 = bf2f(qkvb[base]),          q2 = bf2f(qkvb[base + 64]);
    float k1 = bf2f(qkvb[base + HID]),    k2 = bf2f(qkvb[base + HID + 64]);
    float qr = c*q1 - sn*q2, qi = sn*q1 + c*q2;
    float kr = c*k1 - sn*k2, ki = sn*k1 + c*k2;
    const float SCQ = 0.12751743232994544f;   // (1/sqrt(128)) * log2e
    size_t o = (size_t)m*HID + hh*D_ + j;
    kout[o] = kr; kout[o + 64] = ki;
    qb[o] = f2bf(qr*SCQ); qb[o + 64] = f2bf(qi*SCQ);
    size_t fo = ((size_t)(b*L_ + POS_ + s)*H_ + hh)*D_ + j;
    kf[fo] = f2bf(kr); kf[fo + 64] = f2bf(ki);
    return;
  }
  int vb = blk - 8192;
  int tt = vb & 31, h = (vb >> 5) & 15, b = vb >> 9;
  int t0 = tt * 64;
  int d0 = (tid & 31) * 4, tr = tid >> 5;
  #pragma unroll
  for (int pass=0; pass<8; ++pass){
    int t = tr + pass*8;
    int gt = t0 + t;
    us4 o;
    if (gt < POS_){
      float4 v4 = *(const float4*)(vc + (((size_t)(b*2*POS_ + gt))*H_ + h)*D_ + d0);
      o[0]=f2bf(v4.x); o[1]=f2bf(v4.y); o[2]=f2bf(v4.z); o[3]=f2bf(v4.w);
    } else {
      o = *(const us4*)(qkvb + (size_t)(b*S_ + gt - POS_)*NQKV + 2*HID + h*D_ + d0);
      float4 vf4;
      vf4.x = bf2f(o[0]); vf4.y = bf2f(o[1]); vf4.z = bf2f(o[2]); vf4.w = bf2f(o[3]);
      *(float4*)(vout + (size_t)(b*S_ + gt - POS_)*HID + h*D_ + d0) = vf4;
    }
    *(us4*)(&T[t*130 + d0]) = o;
  }
  __syncthreads();
  int d = tid >> 1, th = (tid & 1) * 32;
  uint4 buf4[4];
  unsigned short* buf = (unsigned short*)buf4;
  #pragma unroll
  for (int e=0;e<32;++e) buf[e] = T[(th+e)*130 + d];
  unsigned short* dst = vt + (((size_t)(b*H_ + h)*D_ + d)*L_) + t0 + th;
  #pragma unroll
  for (int c=0;c<4;++c) *(uint4*)(dst + c*8) = buf4[c];
}

// QKV GEMM, XCD-swizzled (each XCD owns 6 B-columns: 3.1 MB < 4 MB L2).
__global__ __launch_bounds__(256) void k_gemm(const unsigned short* __restrict__ A,
    const unsigned short* __restrict__ Bm, const float* __restrict__ bias,
    unsigned short* __restrict__ Cout, int Md, int Nd, int Kd)
{
  __shared__ unsigned short As[128*64];
  __shared__ unsigned short Bs[128*64];
  const int tid = threadIdx.x;
  const int lane = tid & 63, w = tid >> 6;
  const int wr = w >> 1, wc = w & 1;
  const int lg = lane >> 4, lr = lane & 15;
  const int xcd = blockIdx.x & 7, kk = blockIdx.x >> 3;
  const int tn = xcd*6 + (kk % 6);
  const int tm = kk / 6;
  f32x4 acc[4][4];
  #pragma unroll
  for (int i=0;i<4;++i)
    #pragma unroll
    for (int j=0;j<4;++j){ f32x4 z = {0.f,0.f,0.f,0.f}; acc[i][j] = z; }

  for (int k0 = 0; k0 < Kd; k0 += 64){
    #pragma unroll
    for (int j=0;j<4;++j){
      int chunk = j*256 + w*64 + lane;
      int row = chunk >> 3, cc = chunk & 7;
      int ccs = cc ^ (row & 7);
      const unsigned short* ga = A  + (size_t)(tm*128 + row)*Kd + k0 + ccs*8;
      __builtin_amdgcn_global_load_lds((gp_t)ga,
          (lp_t)((char*)As + (j*256 + w*64)*16), 16, 0, 0);
      const unsigned short* gb = Bm + (size_t)(tn*128 + row)*Kd + k0 + ccs*8;
      __builtin_amdgcn_global_load_lds((gp_t)gb,
          (lp_t)((char*)Bs + (j*256 + w*64)*16), 16, 0, 0);
    }
    __syncthreads();
    #pragma unroll
    for (int ks=0; ks<2; ++ks){
      bf16x8 af[4], bf[4];
      #pragma unroll
      for (int mi=0;mi<4;++mi){
        int row = wr*64 + mi*16 + lr;
        int byte = (row*128 + ks*64 + lg*16) ^ ((row & 7) << 4);
        af[mi] = *(const bf16x8*)((const char*)As + byte);
      }
      #pragma unroll
      for (int ni=0;ni<4;++ni){
        int row = wc*64 + ni*16 + lr;
        int byte = (row*128 + ks*64 + lg*16) ^ ((row & 7) << 4);
        bf[ni] = *(const bf16x8*)((const char*)Bs + byte);
      }
      #pragma unroll
      for (int mi=0;mi<4;++mi)
        #pragma unroll
        for (int ni=0;ni<4;++ni)
          acc[mi][ni] = __builtin_amdgcn_mfma_f32_16x16x32_bf16(af[mi], bf[ni], acc[mi][ni], 0, 0, 0);
    }
    __syncthreads();
  }
  #pragma unroll
  for (int mi=0;mi<4;++mi)
    #pragma unroll
    for (int ni=0;ni<4;++ni){
      int col = tn*128 + wc*64 + ni*16 + lr;
      float bv = bias[col];
      #pragma unroll
      for (int i=0;i<4;++i){
        int row = tm*128 + wr*64 + mi*16 + lg*4 + i;
        Cout[(size_t)row*Nd + col] = f2bf(acc[mi][ni][i] + bv);
      }
    }
}

// Split-K=4 out-proj GEMM, XCD-swizzled; bf16 quarter-partials.
__global__ __launch_bounds__(256) void k_gemm_sk(const unsigned short* __restrict__ A,
    const unsigned short* __restrict__ Bm, unsigned short* __restrict__ Cp, int Md, int Nd, int Kd)
{
  __shared__ unsigned short As[128*64];
  __shared__ unsigned short Bs[128*64];
  const int tid = threadIdx.x;
  const int lane = tid & 63, w = tid >> 6;
  const int wr = w >> 1, wc = w & 1;
  const int lg = lane >> 4, lr = lane & 15;
  const int quarter = blockIdx.x >> 8;
  const int lbid = blockIdx.x & 255;
  const int xcd = lbid & 7, kk = lbid >> 3;
  const int tn = xcd*2 + (kk & 1);
  const int tm = kk >> 1;
  const int koff = quarter * (Kd >> 2);
  f32x4 acc[4][4];
  #pragma unroll
  for (int i=0;i<4;++i)
    #pragma unroll
    for (int j=0;j<4;++j){ f32x4 z = {0.f,0.f,0.f,0.f}; acc[i][j] = z; }

  for (int k0 = koff; k0 < koff + (Kd >> 2); k0 += 64){
    #pragma unroll
    for (int j=0;j<4;++j){
      int chunk = j*256 + w*64 + lane;
      int row = chunk >> 3, cc = chunk & 7;
      int ccs = cc ^ (row & 7);
      const unsigned short* ga = A  + (size_t)(tm*128 + row)*Kd + k0 + ccs*8;
      __builtin_amdgcn_global_load_lds((gp_t)ga,
          (lp_t)((char*)As + (j*256 + w*64)*16), 16, 0, 0);
      const unsigned short* gb = Bm + (size_t)(tn*128 + row)*Kd + k0 + ccs*8;
      __builtin_amdgcn_global_load_lds((gp_t)gb,
          (lp_t)((char*)Bs + (j*256 + w*64)*16), 16, 0, 0);
    }
    __syncthreads();
    #pragma unroll
    for (int ks=0; ks<2; ++ks){
      bf16x8 af[4], bf[4];
      #pragma unroll
      for (int mi=0;mi<4;++mi){
        int row = wr*64 + mi*16 + lr;
        int byte = (row*128 + ks*64 + lg*16) ^ ((row & 7) << 4);
        af[mi] = *(const bf16x8*)((const char*)As + byte);
      }
      #pragma unroll
      for (int ni=0;ni<4;++ni){
        int row = wc*64 + ni*16 + lr;
        int byte = (row*128 + ks*64 + lg*16) ^ ((row & 7) << 4);
        bf[ni] = *(const bf16x8*)((const char*)Bs + byte);
      }
      #pragma unroll
      for (int mi=0;mi<4;++mi)
        #pragma unroll
        for (int ni=0;ni<4;++ni)
          acc[mi][ni] = __builtin_amdgcn_mfma_f32_16x16x32_bf16(af[mi], bf[ni], acc[mi][ni], 0, 0, 0);
    }
    __syncthreads();
  }
  unsigned short* Cb = Cp + (size_t)quarter*Md*Nd;
  #pragma unroll
  for (int mi=0;mi<4;++mi)
    #pragma unroll
    for (int ni=0;ni<4;++ni){
      int col = tn*128 + wc*64 + ni*16 + lr;
      #pragma unroll
      for (int i=0;i<4;++i){
        int row = tm*128 + wr*64 + mi*16 + lg*4 + i;
        Cb[(size_t)row*Nd + col] = f2bf(acc[mi][ni][i]);
      }
    }
}

// out = sum(Cp[0..3]) + bias  (bf16 partials -> fp32 out)
__global__ void k_red(const unsigned short* __restrict__ Cp, const float* __restrict__ bias,
                      float* __restrict__ out){
  int i = (blockIdx.x*256 + threadIdx.x)*4;
  if (i >= 2048*2048) return;
  int col = i & 2047;
  float4 bv = *(const float4*)(bias + col);
  float4 r; r.x = bv.x; r.y = bv.y; r.z = bv.z; r.w = bv.w;
  #pragma unroll
  for (int q=0; q<4; ++q){
    us4 a = *(const us4*)(Cp + (size_t)q*4194304 + i);
    r.x += bf2f(a[0]); r.y += bf2f(a[1]); r.z += bf2f(a[2]); r.w += bf2f(a[3]);
  }
  *(float4*)(out + i) = r;
}

// Flash attention: 32 q/wave, split=2, no max-tracking, l via MFMA ones-column.
// T5 setprio around the MFMA clusters (m191: attn-positive).
__global__ __launch_bounds__(256, 2) void k_attn_part(const unsigned short* __restrict__ Q,
    const unsigned short* __restrict__ Kf, const unsigned short* __restrict__ vt,
    const unsigned short* __restrict__ mf, unsigned short* __restrict__ Opart,
    float* __restrict__ ml)
{
  __shared__ unsigned short Kt[64*128];
  __shared__ unsigned short Vt[144*64];
  __shared__ unsigned short Pw[4][32*64];
  const int tid = threadIdx.x;
  const int lane = tid & 63, w = tid >> 6;
  const int lg = lane >> 4, lr = lane & 15;
  const int hw = blockIdx.x;
  const int xcd = hw & 7, slot = hw >> 3;
  const int g = xcd*8 + (slot >> 3);
  const int qblk = slot & 7;
  const int h = g & 15, b = (g >> 4) & 1, split = g >> 5;
  const int q0 = qblk * 128;
  const int tlo = split * (L_/2);

  {
    uint32_t* vz = (uint32_t*)&Vt[128*64];
    #pragma unroll
    for (int r2=0; r2<2; ++r2){
      int idx2 = tid + r2*256;
      vz[idx2] = (idx2 < 32) ? 0x3F803F80u : 0u;
    }
  }

  bf16x8 qf[2][4];
  #pragma unroll
  for (int qh=0; qh<2; ++qh){
    const unsigned short* qbase = Q + ((size_t)(b*S_ + q0 + w*32 + qh*16 + lr))*HID + h*D_;
    #pragma unroll
    for (int ks=0; ks<4; ++ks)
      qf[qh][ks] = *(const bf16x8*)(qbase + ks*32 + lg*8);
  }
  f32x4 oacc[2][9];
  #pragma unroll
  for (int qh=0; qh<2; ++qh)
    #pragma unroll
    for (int i=0;i<9;++i){ f32x4 z = {0.f,0.f,0.f,0.f}; oacc[qh][i] = z; }
  const unsigned short* vtb = vt + ((size_t)(b*H_ + h)*D_)*L_;
  const unsigned short* mfrag[2];
  #pragma unroll
  for (int qh=0; qh<2; ++qh)
    mfrag[qh] = mf + ((size_t)((h & 1)*64 + qblk*8 + w*2 + qh) * 32) * 1024
                   + (size_t)(lg*16 + lr) * 16;

  for (int tof = 0; tof < L_/2; tof += 64){
    int t0 = tlo + tof;
    #pragma unroll
    for (int j=0;j<4;++j){
      int chunk = j*256 + w*64 + lane;
      int row = chunk >> 4, cc = chunk & 15;
      int ccs = cc ^ (row & 7);
      const unsigned short* gk = Kf + ((size_t)(b*L_ + t0 + row)*H_ + h)*D_ + ccs*8;
      __builtin_amdgcn_global_load_lds((gp_t)gk,
          (lp_t)((char*)Kt + (j*256 + w*64)*16), 16, 0, 0);
    }
    #pragma unroll
    for (int j=0;j<4;++j){
      int chunk = j*256 + w*64 + lane;
      int row = chunk >> 3, cc = chunk & 7;
      int ccs = cc ^ (row & 7);
      const unsigned short* gv = vtb + (size_t)row*L_ + t0 + ccs*8;
      __builtin_amdgcn_global_load_lds((gp_t)gv,
          (lp_t)((char*)Vt + (j*256 + w*64)*16), 16, 0, 0);
    }
    union { us8 v[2]; unsigned short s[16]; } mu[2];
    #pragma unroll
    for (int qh=0; qh<2; ++qh){
      const us8* mv = (const us8*)(mfrag[qh] + (size_t)(tof >> 6)*1024 + (size_t)(split ? 16384 : 0));
      mu[qh].v[0] = mv[0]; mu[qh].v[1] = mv[1];
    }
    __syncthreads();

    f32x4 sc[2][4];
    #pragma unroll
    for (int qh=0; qh<2; ++qh)
      #pragma unroll
      for (int nf=0;nf<4;++nf){ f32x4 z = {0.f,0.f,0.f,0.f}; sc[qh][nf] = z; }
    __builtin_amdgcn_s_setprio(1);
    #pragma unroll
    for (int nf=0;nf<4;++nf){
      #pragma unroll
      for (int ks=0;ks<4;++ks){
        int row = nf*16 + lr;
        int byte = (row*256 + ks*64 + lg*16) ^ ((row & 7) << 4);
        bf16x8 kb = *(const bf16x8*)((const char*)Kt + byte);
        sc[0][nf] = __builtin_amdgcn_mfma_f32_16x16x32_bf16(qf[0][ks], kb, sc[0][nf], 0, 0, 0);
        sc[1][nf] = __builtin_amdgcn_mfma_f32_16x16x32_bf16(qf[1][ks], kb, sc[1][nf], 0, 0, 0);
      }
    }
    __builtin_amdgcn_s_setprio(0);

    #pragma unroll
    for (int qh=0; qh<2; ++qh)
      #pragma unroll
      for (int nf=0;nf<4;++nf)
        #pragma unroll
        for (int i=0;i<4;++i){
          float p = __builtin_amdgcn_exp2f(sc[qh][nf][i] + bf2f(mu[qh].s[nf*4+i]));
          int row = qh*16 + lg*4 + i;
          int byte = (row*128 + nf*32 + lr*2) ^ ((row & 7) << 4);
          *(unsigned short*)((char*)(&Pw[w][0]) + byte) = f2bf(p);
        }
    __asm__ volatile("s_waitcnt lgkmcnt(0)" ::: "memory");

    bf16x8 pa[2][2];
    #pragma unroll
    for (int qh=0; qh<2; ++qh)
      #pragma unroll
      for (int ks2=0; ks2<2; ++ks2){
        int row = qh*16 + lr;
        int pbyte = (row*128 + ks2*64 + lg*16) ^ ((row & 7) << 4);
        pa[qh][ks2] = *(const bf16x8*)((const char*)(&Pw[w][0]) + pbyte);
      }
    __builtin_amdgcn_s_setprio(1);
    #pragma unroll
    for (int ks2=0; ks2<2; ++ks2){
      #pragma unroll
      for (int df=0;df<9;++df){
        int vrow = df*16 + lr;
        int vbyte = (vrow*128 + ks2*64 + lg*16) ^ ((vrow & 7) << 4);
        bf16x8 vb = *(const bf16x8*)((const char*)Vt + vbyte);
        oacc[0][df] = __builtin_amdgcn_mfma_f32_16x16x32_bf16(pa[0][ks2], vb, oacc[0][df], 0, 0, 0);
        oacc[1][df] = __builtin_amdgcn_mfma_f32_16x16x32_bf16(pa[1][ks2], vb, oacc[1][df], 0, 0, 0);
      }
    }
    __builtin_amdgcn_s_setprio(0);
    __syncthreads();
  }

  #pragma unroll
  for (int qh=0; qh<2; ++qh){
    size_t rbase = (size_t)(b*H_ + h)*S_ + q0 + w*32 + qh*16;
    size_t pbase = (size_t)split*(B_*H_*S_) + rbase;
    #pragma unroll
    for (int df=0;df<8;++df)
      #pragma unroll
      for (int i=0;i<4;++i)
        Opart[(pbase + lg*4 + i)*D_ + df*16 + lr] = f2bf(oacc[qh][df][i]);
    if (lr == 0){
      #pragma unroll
      for (int i=0;i<4;++i){
        size_t row = pbase + lg*4 + i;
        ml[row*2]     = 0.0f;
        ml[row*2 + 1] = oacc[qh][8][i];
      }
    }
  }
}

// Combine 2 splits (weights exactly 1 since m==0).  bf16 Opart.
__global__ void k_comb(const unsigned short* __restrict__ Opart, const float* __restrict__ ml,
                       unsigned short* __restrict__ Ob)
{
  const int NR = B_*H_*S_;
  int idx = blockIdx.x*256 + threadIdx.x;
  int r = idx >> 5, dq = (idx & 31) * 4;
  float l0 = ml[(size_t)r*2 + 1];
  float l1 = ml[(size_t)(NR + r)*2 + 1];
  float inv = 1.0f / (l0 + l1);
  us4 o0 = *(const us4*)(Opart + (size_t)r*D_ + dq);
  us4 o1 = *(const us4*)(Opart + (size_t)(NR + r)*D_ + dq);
  int s = r & (S_-1), bh = r >> 10;
  int b = bh >> 4, h = bh & 15;
  size_t o = ((size_t)(b*S_ + s))*HID + h*D_ + dq;
  us4 w;
  w[0] = f2bf((bf2f(o0[0]) + bf2f(o1[0]))*inv);
  w[1] = f2bf((bf2f(o0[1]) + bf2f(o1[1]))*inv);
  w[2] = f2bf((bf2f(o0[2]) + bf2f(o1[2]))*inv);
  w[3] = f2bf((bf2f(o0[3]) + bf2f(o1[3]))*inv);
  *(us4*)(Ob + o) = w;
}

extern "C" void kernel_launch(void* const* d_in, const int* in_sizes, int n_in,
                              void* d_out, int out_size, void* d_ws, size_t ws_size,
                              hipStream_t stream){
  const float* x    = (const float*)d_in[0];
  const float* mask = (const float*)d_in[1];
  const float* cosb = (const float*)d_in[2];
  const float* sinb = (const float*)d_in[3];
  const float* kc   = (const float*)d_in[4];
  const float* vc   = (const float*)d_in[5];
  const float* Wq   = (const float*)d_in[8];
  const float* bq   = (const float*)d_in[9];
  const float* Wk   = (const float*)d_in[10];
  const float* bk   = (const float*)d_in[11];
  const float* Wv   = (const float*)d_in[12];
  const float* bv   = (const float*)d_in[13];
  const float* Wo   = (const float*)d_in[14];
  const float* bo   = (const float*)d_in[15];

  float* out  = (float*)d_out;
  float* kout = out + 4194304;
  float* vout = out + 8388608;

  char* ws = (char*)d_ws;
  unsigned short* qkvb  = (unsigned short*)(ws);             // 25165824 B (dead after k_rv)
  unsigned short* Opart = (unsigned short*)(ws);             // 16777216 B bf16, overlays dead qkvb
  unsigned short* Cp    = (unsigned short*)(ws);             // 33554432 B bf16 (4 quarters), after k_comb
  float*          ml    = (float*)(ws + 33554432);           // 524288 B
  unsigned short* xb    = (unsigned short*)(ws + 50331648);  // 8388608
  unsigned short* Wqkvb = (unsigned short*)(ws + 58720256);  // 25165824
  unsigned short* mf    = (unsigned short*)(ws + 83886080);  // 8388608
  unsigned short* Wob   = (unsigned short*)(ws + 92274688);  // 8388608
  float*          bqkv  = (float*)(ws + 100663296);          // 24576
  unsigned short* qb    = (unsigned short*)(ws + 100687872); // 8388608
  unsigned short* kf    = (unsigned short*)(ws + 109076480); // 16777216
  unsigned short* vt    = (unsigned short*)(ws + 125853696); // 16777216
  unsigned short* attnb = (unsigned short*)(ws + 142630912); // 8388608

  k_prep<<<25606, 256, 0, stream>>>(Wq, Wk, Wv, Wo, x, mask, kc, bq, bk, bv,
                                    Wqkvb, Wob, xb, mf, kf, bqkv);
  k_gemm<<<768, 256, 0, stream>>>(xb, Wqkvb, bqkv, qkvb, 2048, 6144, 2048);
  k_rv<<<9216, 256, 0, stream>>>(qkvb, cosb, sinb, vc, kout, qb, kf, vt, vout);
  k_attn_part<<<512, 256, 0, stream>>>(qb, kf, vt, mf, Opart, ml);
  k_comb<<<4096, 256, 0, stream>>>(Opart, ml, attnb);
  k_gemm_sk<<<1024, 256, 0, stream>>>(attnb, Wob, Cp, 2048, 2048, 2048);
  k_red<<<4096, 256, 0, stream>>>(Cp, bo, out);

  (void)in_sizes; (void)n_in; (void)out_size; (void)ws_size;
}